// Round 1
// baseline (253.249 us; speedup 1.0000x reference)
//
#include <hip/hip_runtime.h>
#include <hip/hip_bf16.h>

#define BB   256
#define SS   2048
#define DIN  32
#define DSL  64
#define KSEL 8

// ws layout: [0, BB*SS) f32 scores  |  then BB*SS*DSL bf16 h1
// d_out layout: sel [B,K,64] | ctx [B,64] | attnW [B,S]  (f32, concat flat)

static __device__ __forceinline__ float bflo(unsigned int u) {
    return __uint_as_float(u << 16);
}
static __device__ __forceinline__ float bfhi(unsigned int u) {
    return __uint_as_float(u & 0xFFFF0000u);
}

// ---------------- Kernel 1: h1 (bf16) + scores (f32) ----------------
// grid 2048 x 256. Each wave serially processes 64 slots; lane j owns
// output channel j: W1 column in 32 VGPRs, x broadcast via wave-uniform
// loads (scalarized to s_load), 32 FMA/slot + shuffle-reduce for score.
__global__ __launch_bounds__(256, 4)
void k1_mlp_scores(const float* __restrict__ feats,
                   const float* __restrict__ W1, const float* __restrict__ b1,
                   const float* __restrict__ W2, const float* __restrict__ b2,
                   const float* __restrict__ q,
                   float* __restrict__ scores_ws,
                   __hip_bfloat16* __restrict__ h1_ws) {
    const int lane = threadIdx.x & 63;
    const int wave = __builtin_amdgcn_readfirstlane((int)(threadIdx.x >> 6));
    const int rowbase = blockIdx.x * 256 + wave * 64;

    float w1c[DIN];
#pragma unroll
    for (int i = 0; i < DIN; ++i) w1c[i] = W1[i * DSL + lane];
    const float b1j = b1[lane];

    // vj = sum_d W2[j][d]*(q0[d]+q1[d])*0.5*0.125 ; c0 = sum_d b2[d]*(...)
    float vj = 0.f, c0 = 0.f;
    for (int d = 0; d < DSL; ++d) {
        float qd = q[d] + q[DSL + d];
        vj = fmaf(W2[lane * DSL + d], qd, vj);
        c0 = fmaf(b2[d], qd, c0);
    }
    vj *= 0.0625f;  // 0.5 (head mean) * 0.125 (1/sqrt(64))
    c0 *= 0.0625f;

    float myscore = 0.f;
    for (int t = 0; t < 64; ++t) {
        const int row = rowbase + t;  // wave-uniform
        const float4* xp = (const float4*)(feats + (size_t)row * DIN);
        float h = b1j;
#pragma unroll
        for (int i4 = 0; i4 < DIN / 4; ++i4) {
            float4 xv = xp[i4];
            h = fmaf(xv.x, w1c[4 * i4 + 0], h);
            h = fmaf(xv.y, w1c[4 * i4 + 1], h);
            h = fmaf(xv.z, w1c[4 * i4 + 2], h);
            h = fmaf(xv.w, w1c[4 * i4 + 3], h);
        }
        h = fmaxf(h, 0.f);
        h1_ws[(size_t)row * DSL + lane] = __float2bfloat16(h);  // 128B/wave
        float p = h * vj;
#pragma unroll
        for (int off = 1; off < 64; off <<= 1) p += __shfl_xor(p, off);
        float sc = p + c0;
        if (t == lane) myscore = sc;  // stash for coalesced store
    }
    scores_ws[rowbase + lane] = myscore;
}

// ---------------- Kernel 2: softmax + ctx + topk + sel ----------------
__global__ __launch_bounds__(256)
void k2_attend(const float* __restrict__ feats,
               const void* __restrict__ maskp,
               const float* __restrict__ W1, const float* __restrict__ b1,
               const float* __restrict__ W2, const float* __restrict__ b2,
               const float* __restrict__ scores_ws,
               const __hip_bfloat16* __restrict__ h1_ws,
               float* __restrict__ sel_out,
               float* __restrict__ ctx_out,
               float* __restrict__ attn_out) {
    __shared__ float scm[SS];       // masked scores (-inf at masked)
    __shared__ float wbuf[SS];      // exp / attnW
    __shared__ float red[32 * DSL]; // u-reduction scratch
    __shared__ float rv[256];
    __shared__ int   ri[256];
    __shared__ int   topidx[KSEL];
    __shared__ int   maskIsByte;
    __shared__ float ubar[DSL];
    __shared__ float xsel[KSEL][DIN];
    __shared__ float h1sel[KSEL][DSL];

    const int t = threadIdx.x;
    const int b = blockIdx.x;

    // --- mask dtype detection: int32 {0,1} has zero bytes at %4!=0 ---
    if (t == 0) maskIsByte = 0;
    __syncthreads();
    {
        unsigned int u = ((const unsigned int*)maskp)[t];  // first 1KB
        if ((u & 0xFFFFFF00u) != 0u) atomicOr(&maskIsByte, 1);
    }
    __syncthreads();
    const bool mbyte = (maskIsByte != 0);

    // --- Phase A: load + mask scores ---
    for (int s = t; s < SS; s += 256) {
        float v = scores_ws[(size_t)b * SS + s];
        bool mk = mbyte ? (((const unsigned char*)maskp)[(size_t)b * SS + s] != 0)
                        : (((const int*)maskp)[(size_t)b * SS + s] != 0);
        scm[s] = mk ? v : -INFINITY;
    }
    __syncthreads();

    // --- Phase B: masked softmax -> attnW ---
    float lm = -INFINITY;
    for (int s = t; s < SS; s += 256) lm = fmaxf(lm, scm[s]);
    rv[t] = lm;
    __syncthreads();
    for (int st = 128; st > 0; st >>= 1) {
        if (t < st) rv[t] = fmaxf(rv[t], rv[t + st]);
        __syncthreads();
    }
    const float m = rv[0];
    __syncthreads();

    float lz = 0.f;
    for (int s = t; s < SS; s += 256) {
        float e = __expf(scm[s] - m);  // exp(-inf)=0 for masked
        wbuf[s] = e;
        lz += e;
    }
    rv[t] = lz;
    __syncthreads();
    for (int st = 128; st > 0; st >>= 1) {
        if (t < st) rv[t] += rv[t + st];
        __syncthreads();
    }
    const float Z = rv[0];
    __syncthreads();
    const float invZ = 1.f / Z;
    for (int s = t; s < SS; s += 256) {
        float w = wbuf[s] * invZ;
        wbuf[s] = w;
        attn_out[(size_t)b * SS + s] = w;
    }
    __syncthreads();

    // --- Phase C: u[j] = sum_s attnW[s]*h1[s][j]  (bf16 h1, coalesced x8) ---
    const int j0 = (t & 7) * 8;
    const int sg = t >> 3;  // 0..31
    float u8[8] = {0.f, 0.f, 0.f, 0.f, 0.f, 0.f, 0.f, 0.f};
    const __hip_bfloat16* hb = h1_ws + (size_t)b * SS * DSL;
    for (int k = 0; k < 64; ++k) {
        int s = sg + (k << 5);
        float w = wbuf[s];
        uint4 hv = *(const uint4*)(hb + (size_t)s * DSL + j0);
        u8[0] = fmaf(w, bflo(hv.x), u8[0]);
        u8[1] = fmaf(w, bfhi(hv.x), u8[1]);
        u8[2] = fmaf(w, bflo(hv.y), u8[2]);
        u8[3] = fmaf(w, bfhi(hv.y), u8[3]);
        u8[4] = fmaf(w, bflo(hv.z), u8[4]);
        u8[5] = fmaf(w, bfhi(hv.z), u8[5]);
        u8[6] = fmaf(w, bflo(hv.w), u8[6]);
        u8[7] = fmaf(w, bfhi(hv.w), u8[7]);
    }
    {
        float* rr = red + sg * DSL + j0;
#pragma unroll
        for (int mm = 0; mm < 8; ++mm) rr[mm] = u8[mm];
    }
    __syncthreads();
    if (t < DSL) {
        float acc = 0.f;
        for (int g = 0; g < 32; ++g) acc += red[g * DSL + t];
        ubar[t] = acc;
    }
    __syncthreads();

    // --- Phase D: ctx = u @ W2 + b2 ---
    if (t < DSL) {
        float acc = b2[t];
        for (int jj = 0; jj < DSL; ++jj) acc = fmaf(ubar[jj], W2[jj * DSL + t], acc);
        ctx_out[(size_t)b * DSL + t] = acc;
    }
    __syncthreads();

    // --- Phase E: top-K (descending value, ties -> lower index) ---
    for (int k = 0; k < KSEL; ++k) {
        int base = t * 8;
        float bv = scm[base];
        int bi = base;
        for (int s = base + 1; s < base + 8; ++s) {
            float v = scm[s];
            if (v > bv) { bv = v; bi = s; }  // strict > keeps lowest index
        }
        rv[t] = bv; ri[t] = bi;
        __syncthreads();
        for (int st = 128; st > 0; st >>= 1) {
            if (t < st) {
                float ov = rv[t + st]; int oi = ri[t + st];
                if (ov > rv[t] || (ov == rv[t] && oi < ri[t])) { rv[t] = ov; ri[t] = oi; }
            }
            __syncthreads();
        }
        if (t == 0) { topidx[k] = ri[0]; scm[ri[0]] = -INFINITY; }
        __syncthreads();
    }

    // --- Phase F: sel = full f32 MLP recompute of the K selected rows ---
    if (t < KSEL * DIN) {
        int k = t / DIN, i = t % DIN;
        xsel[k][i] = feats[((size_t)b * SS + topidx[k]) * DIN + i];
    }
    __syncthreads();
    const int wv = t >> 6, ln = t & 63;
    for (int k = wv; k < KSEL; k += 4) {
        float h = b1[ln];
        for (int i = 0; i < DIN; ++i) h = fmaf(xsel[k][i], W1[i * DSL + ln], h);
        h1sel[k][ln] = fmaxf(h, 0.f);
    }
    __syncthreads();
    for (int k = wv; k < KSEL; k += 4) {
        float acc = b2[ln];
        for (int jj = 0; jj < DSL; ++jj)
            acc = fmaf(h1sel[k][jj], W2[jj * DSL + ln], acc);
        sel_out[((size_t)b * KSEL + k) * DSL + ln] = acc;
    }
}

extern "C" void kernel_launch(void* const* d_in, const int* in_sizes, int n_in,
                              void* d_out, int out_size, void* d_ws, size_t ws_size,
                              hipStream_t stream) {
    const float* feats = (const float*)d_in[0];
    const void*  mask  = d_in[1];
    const float* W1 = (const float*)d_in[2];
    const float* b1 = (const float*)d_in[3];
    const float* W2 = (const float*)d_in[4];
    const float* b2 = (const float*)d_in[5];
    const float* q  = (const float*)d_in[6];

    float* scores_ws = (float*)d_ws;
    __hip_bfloat16* h1_ws =
        (__hip_bfloat16*)((char*)d_ws + (size_t)BB * SS * sizeof(float));

    float* sel_out  = (float*)d_out;                       // B*K*64
    float* ctx_out  = sel_out + (size_t)BB * KSEL * DSL;   // B*64
    float* attn_out = ctx_out + (size_t)BB * DSL;          // B*S

    hipLaunchKernelGGL(k1_mlp_scores, dim3(BB * SS / 256), dim3(256), 0, stream,
                       feats, W1, b1, W2, b2, q, scores_ws, h1_ws);
    hipLaunchKernelGGL(k2_attend, dim3(BB), dim3(256), 0, stream,
                       feats, mask, W1, b1, W2, b2, scores_ws, h1_ws,
                       sel_out, ctx_out, attn_out);
}

// Round 5
// 195.392 us; speedup vs baseline: 1.2961x; 1.2961x over previous
//
#include <hip/hip_runtime.h>
#include <hip/hip_bf16.h>

#define BB   256
#define SS   2048
#define DIN  32
#define DSL  64
#define KSEL 8

// ws layout: [0, BB*SS) f32 scores  |  then BB*SS*DSL bf16 h1
// d_out layout: sel [B,K,64] | ctx [B,64] | attnW [B,S]  (f32, concat flat)

static __device__ __forceinline__ float bflo(unsigned int u) {
    return __uint_as_float(u << 16);
}
static __device__ __forceinline__ float bfhi(unsigned int u) {
    return __uint_as_float(u & 0xFFFF0000u);
}
static __device__ __forceinline__ unsigned int bf16bits(float f) {
    __hip_bfloat16 h = __float2bfloat16(f);  // RNE
    unsigned short u;
    __builtin_memcpy(&u, &h, 2);
    return (unsigned int)u;
}

// ---------------- Kernel 1: h1 (bf16) + scores (f32), slot-per-lane ----------
// grid 1024 x 256. Each wave handles 128 slots (2 per lane). Lane keeps its two
// x-rows in VGPRs; W1 columns (+b1,v) broadcast from LDS (wave-uniform
// ds_read_b128 = free). No shuffles, no serial per-slot chains.
__global__ __launch_bounds__(256, 4)
void k1_mlp_scores(const float* __restrict__ feats,
                   const float* __restrict__ W1, const float* __restrict__ b1,
                   const float* __restrict__ W2, const float* __restrict__ b2,
                   const float* __restrict__ q,
                   float* __restrict__ scores_ws,
                   __hip_bfloat16* __restrict__ h1_ws) {
    // Wl row j (stride 36 floats = 144B, 16B-aligned): [w0..w31, b1j, vj, pad, pad]
    __shared__ float Wl[DSL * 36 + 1];
    const int t = threadIdx.x;

    // prologue: build W1^T + v in LDS once per block (W2 read once per block)
    if (t < DSL) {
        const int j = t;
#pragma unroll
        for (int i = 0; i < DIN; ++i) Wl[j * 36 + i] = W1[i * DSL + j];
        float vj = 0.f;
        for (int d = 0; d < DSL; ++d)
            vj = fmaf(W2[j * DSL + d], q[d] + q[DSL + d], vj);
        Wl[j * 36 + 32] = b1[j];
        Wl[j * 36 + 33] = vj * 0.0625f;  // 0.5 (head mean) * 0.125 (1/sqrt(64))
    } else if (t == DSL) {
        float c0 = 0.f;
        for (int d = 0; d < DSL; ++d)
            c0 = fmaf(b2[d], q[d] + q[DSL + d], c0);
        Wl[DSL * 36] = c0 * 0.0625f;
    }
    __syncthreads();

    const int lane = t & 63;
    const int wave = t >> 6;
    const long base = (long)blockIdx.x * 512 + (long)wave * 128;
    const long rA = base + lane;
    const long rB = base + 64 + lane;

    // load both x rows into VGPRs (16 independent 16B loads, all in flight)
    float xa[DIN], xb[DIN];
    {
        const float4* pa = (const float4*)(feats + rA * DIN);
        const float4* pb = (const float4*)(feats + rB * DIN);
#pragma unroll
        for (int i4 = 0; i4 < DIN / 4; ++i4) {
            float4 va = pa[i4];
            xa[4 * i4 + 0] = va.x; xa[4 * i4 + 1] = va.y;
            xa[4 * i4 + 2] = va.z; xa[4 * i4 + 3] = va.w;
        }
#pragma unroll
        for (int i4 = 0; i4 < DIN / 4; ++i4) {
            float4 vb = pb[i4];
            xb[4 * i4 + 0] = vb.x; xb[4 * i4 + 1] = vb.y;
            xb[4 * i4 + 2] = vb.z; xb[4 * i4 + 3] = vb.w;
        }
    }

    const float c0 = Wl[DSL * 36];
    float sA = c0, sB = c0;
    __hip_bfloat16* hA = h1_ws + rA * DSL;
    __hip_bfloat16* hB = h1_ws + rB * DSL;

    for (int jb = 0; jb < 8; ++jb) {
        unsigned int pkA[4], pkB[4];
#pragma unroll
        for (int jo = 0; jo < 8; ++jo) {
            const int j = jb * 8 + jo;
            const float4* wr4 = (const float4*)&Wl[j * 36];
            const float2 bv = *(const float2*)&Wl[j * 36 + 32];  // (b1j, vj)
            float ha = bv.x, hb2 = bv.x;
#pragma unroll
            for (int i4 = 0; i4 < DIN / 4; ++i4) {
                float4 w = wr4[i4];
                ha  = fmaf(xa[4 * i4 + 0], w.x, ha);
                hb2 = fmaf(xb[4 * i4 + 0], w.x, hb2);
                ha  = fmaf(xa[4 * i4 + 1], w.y, ha);
                hb2 = fmaf(xb[4 * i4 + 1], w.y, hb2);
                ha  = fmaf(xa[4 * i4 + 2], w.z, ha);
                hb2 = fmaf(xb[4 * i4 + 2], w.z, hb2);
                ha  = fmaf(xa[4 * i4 + 3], w.w, ha);
                hb2 = fmaf(xb[4 * i4 + 3], w.w, hb2);
            }
            ha  = fmaxf(ha, 0.f);
            hb2 = fmaxf(hb2, 0.f);
            sA = fmaf(ha, bv.y, sA);
            sB = fmaf(hb2, bv.y, sB);
            if ((jo & 1) == 0) {
                pkA[jo >> 1] = bf16bits(ha);
                pkB[jo >> 1] = bf16bits(hb2);
            } else {
                pkA[jo >> 1] |= bf16bits(ha) << 16;
                pkB[jo >> 1] |= bf16bits(hb2) << 16;
            }
        }
        *(uint4*)(hA + jb * 8) = make_uint4(pkA[0], pkA[1], pkA[2], pkA[3]);
        *(uint4*)(hB + jb * 8) = make_uint4(pkB[0], pkB[1], pkB[2], pkB[3]);
    }
    scores_ws[rA] = sA;  // coalesced
    scores_ws[rB] = sB;
}

// ---------------- Kernel 2: softmax + ctx + topk + sel ----------------
__global__ __launch_bounds__(256)
void k2_attend(const float* __restrict__ feats,
               const void* __restrict__ maskp,
               const float* __restrict__ W1, const float* __restrict__ b1,
               const float* __restrict__ W2, const float* __restrict__ b2,
               const float* __restrict__ scores_ws,
               const __hip_bfloat16* __restrict__ h1_ws,
               float* __restrict__ sel_out,
               float* __restrict__ ctx_out,
               float* __restrict__ attn_out) {
    __shared__ float scm[SS];        // masked scores (-inf at masked)
    __shared__ float wbuf[SS];       // exp / attnW
    __shared__ float red[4 * DSL];   // cross-wave reduction scratch
    __shared__ float ubar[DSL];
    __shared__ float wredf[4];
    __shared__ float wargv[4];
    __shared__ int   wargi[4];
    __shared__ int   topidx[KSEL];
    __shared__ int   maskIsByte;
    __shared__ float xsel[KSEL][DIN];
    __shared__ float h1sel[KSEL][DSL];

    const int t = threadIdx.x;
    const int b = blockIdx.x;
    const int lane = t & 63;
    const int wv = t >> 6;

    // --- mask dtype detection: int32 {0,1} has zero bytes at %4!=0 ---
    if (t == 0) maskIsByte = 0;
    __syncthreads();
    {
        unsigned int u = ((const unsigned int*)maskp)[t];  // first 1KB
        if ((u & 0xFFFFFF00u) != 0u) atomicOr(&maskIsByte, 1);
    }
    __syncthreads();
    const bool mbyte = (maskIsByte != 0);

    // --- Phase A: load + mask scores ---
    for (int s = t; s < SS; s += 256) {
        float v = scores_ws[(size_t)b * SS + s];
        bool mk = mbyte ? (((const unsigned char*)maskp)[(size_t)b * SS + s] != 0)
                        : (((const int*)maskp)[(size_t)b * SS + s] != 0);
        scm[s] = mk ? v : -INFINITY;
    }
    __syncthreads();

    // --- Phase B: masked softmax -> attnW (wave shuffles, 2 barriers/reduce) ---
    float lm = -INFINITY;
    for (int s = t; s < SS; s += 256) lm = fmaxf(lm, scm[s]);
#pragma unroll
    for (int o = 1; o < 64; o <<= 1) lm = fmaxf(lm, __shfl_xor(lm, o));
    if (lane == 0) wredf[wv] = lm;
    __syncthreads();
    const float m = fmaxf(fmaxf(wredf[0], wredf[1]), fmaxf(wredf[2], wredf[3]));
    __syncthreads();  // protect wredf before re-use

    float lz = 0.f;
    if (m == -INFINITY) {  // all-masked row: reference -> uniform softmax
        for (int s = t; s < SS; s += 256) wbuf[s] = 1.f;
        lz = (float)(SS / 256);
    } else {
        for (int s = t; s < SS; s += 256) {
            float e = __expf(scm[s] - m);  // exp(-inf)=0 for masked
            wbuf[s] = e;
            lz += e;
        }
    }
#pragma unroll
    for (int o = 1; o < 64; o <<= 1) lz += __shfl_xor(lz, o);
    if (lane == 0) wredf[wv] = lz;
    __syncthreads();
    const float Z = wredf[0] + wredf[1] + wredf[2] + wredf[3];
    const float invZ = 1.f / Z;
    for (int s = t; s < SS; s += 256) {
        float w = wbuf[s] * invZ;
        wbuf[s] = w;
        attn_out[(size_t)b * SS + s] = w;
    }
    __syncthreads();

    // --- Phase C: u[j] = sum_s attnW[s]*h1[s][j]  (bf16 h1, coalesced x8) ---
    const int j0 = (t & 7) * 8;
    const int sg = t >> 3;  // 0..31
    float u8[8] = {0.f, 0.f, 0.f, 0.f, 0.f, 0.f, 0.f, 0.f};
    const __hip_bfloat16* hb = h1_ws + (size_t)b * SS * DSL;
    for (int k = 0; k < 64; ++k) {
        int s = sg + (k << 5);
        float w = wbuf[s];
        uint4 hv = *(const uint4*)(hb + (size_t)s * DSL + j0);
        u8[0] = fmaf(w, bflo(hv.x), u8[0]);
        u8[1] = fmaf(w, bfhi(hv.x), u8[1]);
        u8[2] = fmaf(w, bflo(hv.y), u8[2]);
        u8[3] = fmaf(w, bfhi(hv.y), u8[3]);
        u8[4] = fmaf(w, bflo(hv.z), u8[4]);
        u8[5] = fmaf(w, bfhi(hv.z), u8[5]);
        u8[6] = fmaf(w, bflo(hv.w), u8[6]);
        u8[7] = fmaf(w, bfhi(hv.w), u8[7]);
    }
    // reduce the 8 s-subgroups within each wave (lanes differing in bits 3..5)
#pragma unroll
    for (int o = 8; o <= 32; o <<= 1) {
#pragma unroll
        for (int mm = 0; mm < 8; ++mm) u8[mm] += __shfl_xor(u8[mm], o);
    }
    if (lane < 8) {
#pragma unroll
        for (int mm = 0; mm < 8; ++mm) red[wv * DSL + lane * 8 + mm] = u8[mm];
    }
    __syncthreads();
    if (t < DSL) ubar[t] = red[t] + red[DSL + t] + red[2 * DSL + t] + red[3 * DSL + t];
    __syncthreads();

    // --- Phase D: ctx = u @ W2 + b2 (all 4 waves, 16 j's each) ---
    {
        float acc = (wv == 0) ? b2[lane] : 0.f;
        for (int jj = wv * 16; jj < wv * 16 + 16; ++jj)
            acc = fmaf(ubar[jj], W2[jj * DSL + lane], acc);
        red[wv * DSL + lane] = acc;
    }
    __syncthreads();
    if (t < DSL)
        ctx_out[(size_t)b * DSL + t] = red[t] + red[DSL + t] + red[2 * DSL + t] + red[3 * DSL + t];

    // --- Phase E: top-K (descending value, ties -> lower index) ---
    for (int k = 0; k < KSEL; ++k) {
        // seed with element s=t so an all -inf row still yields valid indices
        float bvv = scm[t];
        int bi = t;
#pragma unroll
        for (int kk = 1; kk < SS / 256; ++kk) {  // strided: conflict-free, idx ascending
            int s = t + kk * 256;
            float v = scm[s];
            if (v > bvv) { bvv = v; bi = s; }
        }
#pragma unroll
        for (int o = 1; o < 64; o <<= 1) {
            float ov = __shfl_xor(bvv, o);
            int oi = __shfl_xor(bi, o);
            if (ov > bvv || (ov == bvv && oi < bi)) { bvv = ov; bi = oi; }
        }
        if (lane == 0) { wargv[wv] = bvv; wargi[wv] = bi; }
        __syncthreads();
        if (t == 0) {
            float Bv = wargv[0]; int Bi = wargi[0];
            for (int w2i = 1; w2i < 4; ++w2i) {
                float ov = wargv[w2i]; int oi = wargi[w2i];
                if (ov > Bv || (ov == Bv && oi < Bi)) { Bv = ov; Bi = oi; }
            }
            topidx[k] = Bi;
            scm[Bi] = -INFINITY;
        }
        __syncthreads();
    }

    // --- Phase F: sel = full f32 MLP recompute of the K selected rows ---
    if (t < KSEL * DIN) {
        int k = t >> 5, i = t & 31;
        xsel[k][i] = feats[((size_t)b * SS + topidx[k]) * DIN + i];
    }
    __syncthreads();
    for (int k = wv; k < KSEL; k += 4) {
        float h = b1[lane];
#pragma unroll
        for (int i = 0; i < DIN; ++i) h = fmaf(xsel[k][i], W1[i * DSL + lane], h);
        h1sel[k][lane] = fmaxf(h, 0.f);
    }
    __syncthreads();
    for (int k = wv; k < KSEL; k += 4) {
        float acc = b2[lane];
        for (int jj = 0; jj < DSL; ++jj)
            acc = fmaf(h1sel[k][jj], W2[jj * DSL + lane], acc);
        sel_out[((size_t)b * KSEL + k) * DSL + lane] = acc;
    }
}

extern "C" void kernel_launch(void* const* d_in, const int* in_sizes, int n_in,
                              void* d_out, int out_size, void* d_ws, size_t ws_size,
                              hipStream_t stream) {
    const float* feats = (const float*)d_in[0];
    const void*  mask  = d_in[1];
    const float* W1 = (const float*)d_in[2];
    const float* b1 = (const float*)d_in[3];
    const float* W2 = (const float*)d_in[4];
    const float* b2 = (const float*)d_in[5];
    const float* q  = (const float*)d_in[6];

    float* scores_ws = (float*)d_ws;
    __hip_bfloat16* h1_ws =
        (__hip_bfloat16*)((char*)d_ws + (size_t)BB * SS * sizeof(float));

    float* sel_out  = (float*)d_out;                       // B*K*64
    float* ctx_out  = sel_out + (size_t)BB * KSEL * DSL;   // B*64
    float* attn_out = ctx_out + (size_t)BB * DSL;          // B*S

    hipLaunchKernelGGL(k1_mlp_scores, dim3(BB * SS / 512), dim3(256), 0, stream,
                       feats, W1, b1, W2, b2, q, scores_ws, h1_ws);
    hipLaunchKernelGGL(k2_attend, dim3(BB), dim3(256), 0, stream,
                       feats, mask, W1, b1, W2, b2, scores_ws, h1_ws,
                       sel_out, ctx_out, attn_out);
}

// Round 8
// 167.593 us; speedup vs baseline: 1.5111x; 1.1659x over previous
//
#include <hip/hip_runtime.h>
#include <hip/hip_bf16.h>

#define BB   256
#define SS   2048
#define DIN  32
#define DSL  64
#define KSEL 8

// ws layout: [0, BB*SS) f32 scores  |  then BB*SS*DSL bf16 h1 (TILED)
// h1 tiled layout (elements): elem(r, j) at (r>>6)*4096 + (j>>3)*512 + (r&63)*8 + (j&7)
//   -> k1 writes 16B/lane, lane-contiguous (1KB full-line wave stores)
//   -> k2 reads 16B/lane, 8 lanes cover 128B contiguous per jb-block
// d_out layout: sel [B,K,64] | ctx [B,64] | attnW [B,S]  (f32, concat flat)

static __device__ __forceinline__ float bflo(unsigned int u) {
    return __uint_as_float(u << 16);
}
static __device__ __forceinline__ float bfhi(unsigned int u) {
    return __uint_as_float(u & 0xFFFF0000u);
}
static __device__ __forceinline__ unsigned int bf16bits(float f) {
    __hip_bfloat16 h = __float2bfloat16(f);  // RNE
    unsigned short u;
    __builtin_memcpy(&u, &h, 2);
    return (unsigned int)u;
}

// ---------------- Kernel 1: h1 (bf16, tiled) + scores (f32) ----------------
__global__ __launch_bounds__(256, 4)
void k1_mlp_scores(const float* __restrict__ feats,
                   const float* __restrict__ W1, const float* __restrict__ b1,
                   const float* __restrict__ W2, const float* __restrict__ b2,
                   const float* __restrict__ q,
                   float* __restrict__ scores_ws,
                   unsigned short* __restrict__ h1_ws) {
    // Wl row j (stride 36 floats = 144B, 16B-aligned): [w0..w31, b1j, vj, pad, pad]
    __shared__ float Wl[DSL * 36 + 1];
    const int t = threadIdx.x;

    if (t < DSL) {
        const int j = t;
#pragma unroll
        for (int i = 0; i < DIN; ++i) Wl[j * 36 + i] = W1[i * DSL + j];
        float vj = 0.f;
        for (int d = 0; d < DSL; ++d)
            vj = fmaf(W2[j * DSL + d], q[d] + q[DSL + d], vj);
        Wl[j * 36 + 32] = b1[j];
        Wl[j * 36 + 33] = vj * 0.0625f;  // 0.5 (head mean) * 0.125 (1/sqrt(64))
    } else if (t == DSL) {
        float c0 = 0.f;
        for (int d = 0; d < DSL; ++d)
            c0 = fmaf(b2[d], q[d] + q[DSL + d], c0);
        Wl[DSL * 36] = c0 * 0.0625f;
    }
    __syncthreads();

    const int lane = t & 63;
    const int wave = t >> 6;
    const long base = (long)blockIdx.x * 512 + (long)wave * 128;
    const long rA = base + lane;
    const long rB = base + 64 + lane;
    const long tileA = base >> 6;  // rA's tile; rB's tile = tileA+1

    float xa[DIN], xb[DIN];
    {
        const float4* pa = (const float4*)(feats + rA * DIN);
        const float4* pb = (const float4*)(feats + rB * DIN);
#pragma unroll
        for (int i4 = 0; i4 < DIN / 4; ++i4) {
            float4 va = pa[i4];
            xa[4 * i4 + 0] = va.x; xa[4 * i4 + 1] = va.y;
            xa[4 * i4 + 2] = va.z; xa[4 * i4 + 3] = va.w;
        }
#pragma unroll
        for (int i4 = 0; i4 < DIN / 4; ++i4) {
            float4 vb = pb[i4];
            xb[4 * i4 + 0] = vb.x; xb[4 * i4 + 1] = vb.y;
            xb[4 * i4 + 2] = vb.z; xb[4 * i4 + 3] = vb.w;
        }
    }

    const float c0 = Wl[DSL * 36];
    float sA = c0, sB = c0;
    unsigned short* hA = h1_ws + (tileA << 12) + (lane << 3);
    unsigned short* hB = h1_ws + ((tileA + 1) << 12) + (lane << 3);

    for (int jb = 0; jb < 8; ++jb) {
        unsigned int pkA[4], pkB[4];
#pragma unroll
        for (int jo = 0; jo < 8; ++jo) {
            const int j = jb * 8 + jo;
            const float4* wr4 = (const float4*)&Wl[j * 36];
            const float2 bv = *(const float2*)&Wl[j * 36 + 32];  // (b1j, vj)
            float ha = bv.x, hb2 = bv.x;
#pragma unroll
            for (int i4 = 0; i4 < DIN / 4; ++i4) {
                float4 w = wr4[i4];
                ha  = fmaf(xa[4 * i4 + 0], w.x, ha);
                hb2 = fmaf(xb[4 * i4 + 0], w.x, hb2);
                ha  = fmaf(xa[4 * i4 + 1], w.y, ha);
                hb2 = fmaf(xb[4 * i4 + 1], w.y, hb2);
                ha  = fmaf(xa[4 * i4 + 2], w.z, ha);
                hb2 = fmaf(xb[4 * i4 + 2], w.z, hb2);
                ha  = fmaf(xa[4 * i4 + 3], w.w, ha);
                hb2 = fmaf(xb[4 * i4 + 3], w.w, hb2);
            }
            ha  = fmaxf(ha, 0.f);
            hb2 = fmaxf(hb2, 0.f);
            sA = fmaf(ha, bv.y, sA);
            sB = fmaf(hb2, bv.y, sB);
            if ((jo & 1) == 0) {
                pkA[jo >> 1] = bf16bits(ha);
                pkB[jo >> 1] = bf16bits(hb2);
            } else {
                pkA[jo >> 1] |= bf16bits(ha) << 16;
                pkB[jo >> 1] |= bf16bits(hb2) << 16;
            }
        }
        // coalesced: 64 lanes x 16B = 1KB contiguous per wave store
        *(uint4*)(hA + (jb << 9)) = make_uint4(pkA[0], pkA[1], pkA[2], pkA[3]);
        *(uint4*)(hB + (jb << 9)) = make_uint4(pkB[0], pkB[1], pkB[2], pkB[3]);
    }
    scores_ws[rA] = sA;  // coalesced
    scores_ws[rB] = sB;
}

// ---------------- Kernel 2: softmax + ctx + topk + sel (1024 thr) ----------
#define T2 1024
#define W2C (T2 / 64)  // 16 waves

__global__ __launch_bounds__(T2)
void k2_attend(const float* __restrict__ feats,
               const void* __restrict__ maskp,
               const float* __restrict__ W1, const float* __restrict__ b1,
               const float* __restrict__ W2, const float* __restrict__ b2,
               const float* __restrict__ scores_ws,
               const unsigned short* __restrict__ h1_ws,
               float* __restrict__ sel_out,
               float* __restrict__ ctx_out,
               float* __restrict__ attn_out) {
    __shared__ float scm[SS];          // masked scores (-inf at masked)
    __shared__ float wbuf[SS];         // exp / attnW
    __shared__ float red[W2C * DSL];   // cross-wave reduction scratch
    __shared__ float ubar[DSL];
    __shared__ float wredf[W2C];
    __shared__ float wargv[W2C];
    __shared__ int   wargi[W2C];
    __shared__ int   topidx[KSEL];
    __shared__ int   maskIsByte;
    __shared__ float xsel[KSEL][DIN];
    __shared__ float h1sel[KSEL][DSL];

    const int t = threadIdx.x;
    const int b = blockIdx.x;
    const int lane = t & 63;
    const int wv = t >> 6;

    // --- mask dtype detection: int32 {0,1} has zero bytes at %4!=0 ---
    if (t == 0) maskIsByte = 0;
    __syncthreads();
    {
        unsigned int u = ((const unsigned int*)maskp)[t];  // first 4KB (mask >= 512KB)
        if ((u & 0xFFFFFF00u) != 0u) atomicOr(&maskIsByte, 1);
    }
    __syncthreads();
    const bool mbyte = (maskIsByte != 0);

    // --- Phase A: load + mask scores ---
    for (int s = t; s < SS; s += T2) {
        float v = scores_ws[(size_t)b * SS + s];
        bool mk = mbyte ? (((const unsigned char*)maskp)[(size_t)b * SS + s] != 0)
                        : (((const int*)maskp)[(size_t)b * SS + s] != 0);
        scm[s] = mk ? v : -INFINITY;
    }
    __syncthreads();

    // --- Phase B: masked softmax -> attnW ---
    float lm = -INFINITY;
    for (int s = t; s < SS; s += T2) lm = fmaxf(lm, scm[s]);
#pragma unroll
    for (int o = 1; o < 64; o <<= 1) lm = fmaxf(lm, __shfl_xor(lm, o));
    if (lane == 0) wredf[wv] = lm;
    __syncthreads();
    float m = wredf[0];
#pragma unroll
    for (int i = 1; i < W2C; ++i) m = fmaxf(m, wredf[i]);
    __syncthreads();  // protect wredf before re-use

    float lz = 0.f;
    if (m == -INFINITY) {  // all-masked row: reference -> uniform softmax
        for (int s = t; s < SS; s += T2) wbuf[s] = 1.f;
        lz = (float)(SS / T2);
    } else {
        for (int s = t; s < SS; s += T2) {
            float e = __expf(scm[s] - m);  // exp(-inf)=0 for masked
            wbuf[s] = e;
            lz += e;
        }
    }
#pragma unroll
    for (int o = 1; o < 64; o <<= 1) lz += __shfl_xor(lz, o);
    if (lane == 0) wredf[wv] = lz;
    __syncthreads();
    float Z = wredf[0];
#pragma unroll
    for (int i = 1; i < W2C; ++i) Z += wredf[i];
    const float invZ = 1.f / Z;
    for (int s = t; s < SS; s += T2) {
        float w = wbuf[s] * invZ;
        wbuf[s] = w;
        attn_out[(size_t)b * SS + s] = w;
    }
    __syncthreads();

    // --- Phase C: u[j] = sum_s attnW[s]*h1[s][j]  (tiled bf16 h1) ---
    const int jb = t & 7;        // j-block: j = jb*8 + m
    const int sg = t >> 3;       // 0..127
    float u8[8] = {0.f, 0.f, 0.f, 0.f, 0.f, 0.f, 0.f, 0.f};
    const unsigned short* hb =
        h1_ws + (size_t)b * (SS * DSL)
              + ((size_t)(sg >> 6) << 12) + (jb << 9) + ((sg & 63) << 3);
    for (int k = 0; k < SS / 128; ++k) {  // 16 iters
        float w = wbuf[sg + (k << 7)];
        uint4 hv = *(const uint4*)(hb + ((size_t)k << 13));
        u8[0] = fmaf(w, bflo(hv.x), u8[0]);
        u8[1] = fmaf(w, bfhi(hv.x), u8[1]);
        u8[2] = fmaf(w, bflo(hv.y), u8[2]);
        u8[3] = fmaf(w, bfhi(hv.y), u8[3]);
        u8[4] = fmaf(w, bflo(hv.z), u8[4]);
        u8[5] = fmaf(w, bfhi(hv.z), u8[5]);
        u8[6] = fmaf(w, bflo(hv.w), u8[6]);
        u8[7] = fmaf(w, bfhi(hv.w), u8[7]);
    }
    // sum the 8 sg-subgroups within each wave (lane bits 3..5)
#pragma unroll
    for (int o = 8; o <= 32; o <<= 1) {
#pragma unroll
        for (int mm = 0; mm < 8; ++mm) u8[mm] += __shfl_xor(u8[mm], o);
    }
    if (lane < 8) {
#pragma unroll
        for (int mm = 0; mm < 8; ++mm) red[wv * DSL + lane * 8 + mm] = u8[mm];
    }
    __syncthreads();
    if (t < DSL) {
        float acc = 0.f;
#pragma unroll
        for (int w2i = 0; w2i < W2C; ++w2i) acc += red[w2i * DSL + t];
        ubar[t] = acc;
    }
    __syncthreads();

    // --- Phase D: ctx = u @ W2 + b2 (16 waves, 4 j's each) ---
    {
        float acc = (wv == 0) ? b2[lane] : 0.f;
        for (int jj = wv * 4; jj < wv * 4 + 4; ++jj)
            acc = fmaf(ubar[jj], W2[jj * DSL + lane], acc);
        red[wv * DSL + lane] = acc;
    }
    __syncthreads();
    if (t < DSL) {
        float acc = 0.f;
#pragma unroll
        for (int w2i = 0; w2i < W2C; ++w2i) acc += red[w2i * DSL + t];
        ctx_out[(size_t)b * DSL + t] = acc;
    }

    // --- Phase E: top-K (descending value, ties -> lower index) ---
    for (int k = 0; k < KSEL; ++k) {
        // seed with s=t so an all -inf row still yields valid indices
        float bvv = scm[t];
        int bi = t;
#pragma unroll
        for (int kk = 1; kk < SS / T2; ++kk) {  // ascending index
            int s = t + kk * T2;
            float v = scm[s];
            if (v > bvv) { bvv = v; bi = s; }
        }
#pragma unroll
        for (int o = 1; o < 64; o <<= 1) {
            float ov = __shfl_xor(bvv, o);
            int oi = __shfl_xor(bi, o);
            if (ov > bvv || (ov == bvv && oi < bi)) { bvv = ov; bi = oi; }
        }
        if (lane == 0) { wargv[wv] = bvv; wargi[wv] = bi; }
        __syncthreads();
        if (t == 0) {
            float Bv = wargv[0]; int Bi = wargi[0];
            for (int w2i = 1; w2i < W2C; ++w2i) {
                float ov = wargv[w2i]; int oi = wargi[w2i];
                if (ov > Bv || (ov == Bv && oi < Bi)) { Bv = ov; Bi = oi; }
            }
            topidx[k] = Bi;
            scm[Bi] = -INFINITY;
        }
        __syncthreads();
    }

    // --- Phase F: sel = full f32 MLP recompute of the K selected rows ---
    if (t < KSEL * DIN) {
        int k = t >> 5, i = t & 31;
        xsel[k][i] = feats[((size_t)b * SS + topidx[k]) * DIN + i];
    }
    __syncthreads();
    if (wv < KSEL) {
        const int k = wv;
        float h = b1[lane];
#pragma unroll
        for (int i = 0; i < DIN; ++i) h = fmaf(xsel[k][i], W1[i * DSL + lane], h);
        h1sel[k][lane] = fmaxf(h, 0.f);
    }
    __syncthreads();
    if (wv < KSEL) {
        const int k = wv;
        float acc = b2[lane];
        for (int jj = 0; jj < DSL; ++jj)
            acc = fmaf(h1sel[k][jj], W2[jj * DSL + lane], acc);
        sel_out[((size_t)b * KSEL + k) * DSL + lane] = acc;
    }
}

extern "C" void kernel_launch(void* const* d_in, const int* in_sizes, int n_in,
                              void* d_out, int out_size, void* d_ws, size_t ws_size,
                              hipStream_t stream) {
    const float* feats = (const float*)d_in[0];
    const void*  mask  = d_in[1];
    const float* W1 = (const float*)d_in[2];
    const float* b1 = (const float*)d_in[3];
    const float* W2 = (const float*)d_in[4];
    const float* b2 = (const float*)d_in[5];
    const float* q  = (const float*)d_in[6];

    float* scores_ws = (float*)d_ws;
    unsigned short* h1_ws =
        (unsigned short*)((char*)d_ws + (size_t)BB * SS * sizeof(float));

    float* sel_out  = (float*)d_out;                       // B*K*64
    float* ctx_out  = sel_out + (size_t)BB * KSEL * DSL;   // B*64
    float* attn_out = ctx_out + (size_t)BB * DSL;          // B*S

    hipLaunchKernelGGL(k1_mlp_scores, dim3(BB * SS / 512), dim3(256), 0, stream,
                       feats, W1, b1, W2, b2, q, scores_ws, h1_ws);
    hipLaunchKernelGGL(k2_attend, dim3(BB), dim3(T2), 0, stream,
                       feats, mask, W1, b1, W2, b2, scores_ws, h1_ws,
                       sel_out, ctx_out, attn_out);
}